// Round 11
// baseline (336.278 us; speedup 1.0000x reference)
//
#include <hip/hip_runtime.h>
#include <hip/hip_bf16.h>
#include <math.h>

#define B_  4
#define S_  2048
#define H_  512
#define NH_ 8
#define D_  64

typedef __attribute__((ext_vector_type(8))) short bf16x8;   // 8 bf16 = 4 VGPR
typedef __attribute__((ext_vector_type(4))) float f32x4;
#define MFMA16(a, b, c) __builtin_amdgcn_mfma_f32_16x16x32_bf16(a, b, c, 0, 0, 0)

__device__ __forceinline__ unsigned short f2bf(float f) {
    union { float f; unsigned int i; } x; x.f = f;
    unsigned int i = x.i;
    i += 0x7fffu + ((i >> 16) & 1u);
    return (unsigned short)(i >> 16);
}
// packed fp32 pair -> bf16 pair (RNE), lo in low 16 bits
__device__ __forceinline__ unsigned int pk2(float lo, float hi) {
    union { __hip_bfloat162 h; unsigned int u; } c;
    c.h = __float22bfloat162_rn(make_float2(lo, hi));
    return c.u;
}
// two float4 (8 consecutive fp32) -> one bf16x8 fragment
__device__ __forceinline__ bf16x8 cvt8(const float4 a, const float4 b) {
    union { bf16x8 v; unsigned int u[4]; } c;
    c.u[0] = pk2(a.x, a.y); c.u[1] = pk2(a.z, a.w);
    c.u[2] = pk2(b.x, b.y); c.u[3] = pk2(b.z, b.w);
    return c.v;
}

// ---------------------------------------------------------------------------
// Weight prep: transpose+convert 512x512 fp32 W -> bf16 Wt[n][k] (n-major).
// ---------------------------------------------------------------------------
__global__ __launch_bounds__(256) void prep_w(
    const float* __restrict__ W0, const float* __restrict__ W1,
    const float* __restrict__ W2, const float* __restrict__ W3,
    unsigned short* __restrict__ Wt)
{
    const float* Ws[4] = {W0, W1, W2, W3};
    const float* W = Ws[blockIdx.z];
    unsigned short* Y = Wt + (size_t)blockIdx.z * H_ * H_;
    __shared__ float Tl[64][68];
    const int t = threadIdx.x;
    const int k0 = blockIdx.y * 64, n0 = blockIdx.x * 64;
    #pragma unroll
    for (int i = 0; i < 4; ++i) {
        const int e = (t + 256 * i) * 4;
        const int r = e >> 6, c = e & 63;
        const float4 a = *(const float4*)(W + (size_t)(k0 + r) * H_ + n0 + c);
        Tl[c + 0][r] = a.x; Tl[c + 1][r] = a.y;
        Tl[c + 2][r] = a.z; Tl[c + 3][r] = a.w;
    }
    __syncthreads();
    #pragma unroll
    for (int i = 0; i < 4; ++i) {
        const int e = (t + 256 * i) * 4;
        const int n = e >> 6, c = e & 63;
        uint2 p;
        p.x = pk2(Tl[n][c + 0], Tl[n][c + 1]);
        p.y = pk2(Tl[n][c + 2], Tl[n][c + 3]);
        *(uint2*)(Y + (size_t)(n0 + n) * H_ + k0 + c) = p;
    }
}

// ---------------------------------------------------------------------------
// Fused projections, NO-LDS direct-fragment GEMM. z=0 Q, z=1 K (dual),
// z=2 V (transposed epilogue -> Vt[b,h,d,s]).
// Every MFMA fragment is loaded straight from global (L2-hot after the grid
// swizzle): B = 16B contiguous from pre-transposed bf16 Wt; A = 32B fp32 +
// packed cvt. NO barriers in the K-loop -> latency hidden by wave TLP.
// Grid: x = m-strip (64, XCD-local A reuse), y = n/head (8), z = 3.
// ---------------------------------------------------------------------------
__global__ __launch_bounds__(256, 4) void proj_all(
    const float* __restrict__ q,  const float* __restrict__ k,
    const float* __restrict__ v,  const float* __restrict__ k_b,
    const unsigned short* __restrict__ Wt,
    const float* __restrict__ bq, const float* __restrict__ bk,
    const float* __restrict__ bkb,const float* __restrict__ bv,
    unsigned short* __restrict__ Qf, unsigned short* __restrict__ Kf,
    unsigned short* __restrict__ Vf)
{
    __shared__ unsigned short Vl[64 * 136];   // only used by VT epilogue (17 KB)
    const int z = blockIdx.z;
    const float *X, *bias, *X2 = nullptr, *bias2 = nullptr;
    const unsigned short *Wa, *Wb = nullptr;
    unsigned short* Y;
    bool VT = false;
    const size_t WSZ = (size_t)H_ * H_;
    if (z == 0)      { X = q; Wa = Wt;           bias = bq; Y = Qf; }
    else if (z == 1) { X = k; Wa = Wt + WSZ;     bias = bk;
                       X2 = k_b; Wb = Wt + 2 * WSZ; bias2 = bkb; Y = Kf; }
    else             { X = v; Wa = Wt + 3 * WSZ; bias = bv; Y = Vf; VT = true; }

    const int t = threadIdx.x;
    const int w = t >> 6, lane = t & 63;
    const int quad = lane >> 4, l15 = lane & 15;
    const int m0 = blockIdx.x * 128, n0 = blockIdx.y * 64;
    const int h  = blockIdx.y;

    const f32x4 zero = {0.f, 0.f, 0.f, 0.f};
    f32x4 acc[2][4];
    #pragma unroll
    for (int i = 0; i < 2; ++i)
        #pragma unroll
        for (int j = 0; j < 4; ++j) acc[i][j] = zero;

    const int npass = (X2 != nullptr) ? 2 : 1;
    for (int pass = 0; pass < npass; ++pass) {
        const float* Xp = pass ? X2 : X;
        const unsigned short* Wp = pass ? Wb : Wa;
        #pragma unroll 2
        for (int kb0 = 0; kb0 < H_; kb0 += 64) {
            #pragma unroll
            for (int ks = 0; ks < 2; ++ks) {
                const int kc = kb0 + ks * 32 + quad * 8;
                bf16x8 af[2], bfr[4];
                #pragma unroll
                for (int i = 0; i < 2; ++i) {
                    const float* ap = Xp + (size_t)(m0 + w * 32 + i * 16 + l15) * H_ + kc;
                    af[i] = cvt8(*(const float4*)ap, *(const float4*)(ap + 4));
                }
                #pragma unroll
                for (int j = 0; j < 4; ++j)
                    bfr[j] = *(const bf16x8*)(Wp + (size_t)(n0 + j * 16 + l15) * H_ + kc);
                #pragma unroll
                for (int i = 0; i < 2; ++i)
                    #pragma unroll
                    for (int j = 0; j < 4; ++j)
                        acc[i][j] = MFMA16(af[i], bfr[j], acc[i][j]);
            }
        }
    }

    const int bb = m0 >> 11, s0 = m0 & (S_ - 1);
    if (!VT) {
        #pragma unroll
        for (int i = 0; i < 2; ++i)
            #pragma unroll
            for (int r = 0; r < 4; ++r) {
                const int s = s0 + w * 32 + i * 16 + quad * 4 + r;
                const size_t base = (((size_t)bb * NH_ + h) * S_ + s) * D_;
                #pragma unroll
                for (int j = 0; j < 4; ++j) {
                    const int d = j * 16 + l15;
                    float val = acc[i][j][r] + bias[n0 + d];
                    if (bias2) val += bias2[n0 + d];
                    Y[base + d] = f2bf(val);
                }
            }
    } else {
        // transposed [b,h,d,s]: stage into LDS, store coalesced along s
        #pragma unroll
        for (int i = 0; i < 2; ++i)
            #pragma unroll
            for (int r = 0; r < 4; ++r) {
                const int ml = w * 32 + i * 16 + quad * 4 + r;
                #pragma unroll
                for (int j = 0; j < 4; ++j) {
                    const int d = j * 16 + l15;
                    Vl[d * 136 + ml] = f2bf(acc[i][j][r] + bias[n0 + d]);
                }
            }
        __syncthreads();
        const int d = t >> 2, sg = (t & 3) * 32;
        const size_t vbase = (((size_t)bb * NH_ + h) * D_ + d) * S_ + s0;
        #pragma unroll
        for (int i = 0; i < 8; ++i)
            *(ushort4*)(Y + vbase + sg + i * 4) = *(const ushort4*)&Vl[d * 136 + sg + i * 4];
    }
}

// ---------------------------------------------------------------------------
// MFMA flash attention (unchanged from R10).
// ---------------------------------------------------------------------------
__global__ __launch_bounds__(256) void attn_mfma(
    unsigned short* QHd,
    const unsigned short* __restrict__ Kh, const unsigned short* __restrict__ Vt,
    const int* __restrict__ mask)
{
    const int b = blockIdx.z, h = blockIdx.y;
    const int q0 = blockIdx.x * 128;
    const int t = threadIdx.x;
    const int w = t >> 6, lane = t & 63;
    const int quad = lane >> 4, l15 = lane & 15;

    __shared__ __align__(16) unsigned short Ks[2][64][72];
    __shared__ __align__(16) unsigned short Vs[2][64][72];
    __shared__ __align__(16) unsigned short Ps[128][72];
    __shared__ int mk[2][64];

    const size_t head = ((size_t)b * NH_ + h) * S_;
    unsigned short* Qbase = QHd + head * D_;
    const unsigned short* Kbase = Kh + head * D_;
    const unsigned short* Vbase = Vt + head * D_;

    bf16x8 qf[2][2];
    #pragma unroll
    for (int rt = 0; rt < 2; ++rt)
        #pragma unroll
        for (int ds = 0; ds < 2; ++ds)
            qf[rt][ds] = *(const bf16x8*)(
                Qbase + (size_t)(q0 + w * 32 + rt * 16 + l15) * D_ + ds * 32 + quad * 8);

    const f32x4 zero = {0.f, 0.f, 0.f, 0.f};
    f32x4 O[2][4];
    #pragma unroll
    for (int rt = 0; rt < 2; ++rt)
        #pragma unroll
        for (int dt = 0; dt < 4; ++dt) O[rt][dt] = zero;
    float lsum[2][4] = {};
    const float SC2 = 0.125f * 1.44269504089f;

    #define STAGE(kt_) do {                                                        \
        const int bf_ = (kt_) & 1, k0_ = (kt_) * 64;                               \
        _Pragma("unroll")                                                          \
        for (int i_ = 0; i_ < 4; ++i_) {                                           \
            const int e_ = (t + 256 * i_) * 4;                                     \
            const int r_ = e_ >> 6, c_ = e_ & 63;                                  \
            *(ushort4*)&Ks[bf_][r_][c_] =                                          \
                *(const ushort4*)(Kbase + (size_t)(k0_ + r_) * D_ + c_);           \
            *(ushort4*)&Vs[bf_][r_][c_] =                                          \
                *(const ushort4*)(Vbase + (size_t)r_ * S_ + k0_ + c_);             \
        }                                                                          \
        if (t < 64) mk[bf_][t] = mask[b * S_ + k0_ + t];                           \
    } while (0)

    STAGE(0);
    __syncthreads();

    for (int kt = 0; kt < S_ / 64; ++kt) {
        const int bf = kt & 1;
        if (kt + 1 < S_ / 64) STAGE(kt + 1);

        float pv[2][4][4];
        #pragma unroll
        for (int ct = 0; ct < 4; ++ct) {
            const bf16x8 kf0 = *(const bf16x8*)&Ks[bf][ct * 16 + l15][quad * 8];
            const bf16x8 kf1 = *(const bf16x8*)&Ks[bf][ct * 16 + l15][32 + quad * 8];
            const float msel = (mk[bf][ct * 16 + l15] == 0) ? -1e9f : 0.f;
            #pragma unroll
            for (int rt = 0; rt < 2; ++rt) {
                f32x4 acc = zero;
                acc = MFMA16(qf[rt][0], kf0, acc);
                acc = MFMA16(qf[rt][1], kf1, acc);
                #pragma unroll
                for (int r = 0; r < 4; ++r) {
                    const float p = __builtin_amdgcn_exp2f(fmaf(acc[r], SC2, msel));
                    pv[rt][ct][r] = p;
                    lsum[rt][r] += p;
                }
            }
        }
        #pragma unroll
        for (int rt = 0; rt < 2; ++rt)
            #pragma unroll
            for (int r = 0; r < 4; ++r) {
                const int row = w * 32 + rt * 16 + quad * 4 + r;
                #pragma unroll
                for (int ct = 0; ct < 4; ++ct)
                    Ps[row][ct * 16 + l15] = f2bf(pv[rt][ct][r]);
            }
        bf16x8 pf[2][2];
        #pragma unroll
        for (int rt = 0; rt < 2; ++rt) {
            pf[rt][0] = *(const bf16x8*)&Ps[w * 32 + rt * 16 + l15][quad * 8];
            pf[rt][1] = *(const bf16x8*)&Ps[w * 32 + rt * 16 + l15][32 + quad * 8];
        }
        #pragma unroll
        for (int dt = 0; dt < 4; ++dt) {
            const bf16x8 vf0 = *(const bf16x8*)&Vs[bf][dt * 16 + l15][quad * 8];
            const bf16x8 vf1 = *(const bf16x8*)&Vs[bf][dt * 16 + l15][32 + quad * 8];
            #pragma unroll
            for (int rt = 0; rt < 2; ++rt) {
                O[rt][dt] = MFMA16(pf[rt][0], vf0, O[rt][dt]);
                O[rt][dt] = MFMA16(pf[rt][1], vf1, O[rt][dt]);
            }
        }
        __syncthreads();
    }
    #undef STAGE

    #pragma unroll
    for (int off = 1; off <= 8; off <<= 1)
        #pragma unroll
        for (int rt = 0; rt < 2; ++rt)
            #pragma unroll
            for (int r = 0; r < 4; ++r)
                lsum[rt][r] += __shfl_xor(lsum[rt][r], off, 64);
    float inv[2][4];
    #pragma unroll
    for (int rt = 0; rt < 2; ++rt)
        #pragma unroll
        for (int r = 0; r < 4; ++r) inv[rt][r] = 1.f / lsum[rt][r];
    #pragma unroll
    for (int rt = 0; rt < 2; ++rt)
        #pragma unroll
        for (int dt = 0; dt < 4; ++dt)
            #pragma unroll
            for (int r = 0; r < 4; ++r) {
                const int row = w * 32 + rt * 16 + quad * 4 + r;
                Qbase[(size_t)(q0 + row) * D_ + dt * 16 + l15] =
                    f2bf(O[rt][dt][r] * inv[rt][r]);
            }
}

// ---------------------------------------------------------------------------
// Output GEMM, NO-LDS direct-fragment: Out_f32[m,n] = Hd_bf16@Wot + bo.
// A frags = contiguous 16B bf16 from head-major Hd; B from transposed Wot.
// No LDS, no barriers. Grid: x = m (64), y = n (8).
// ---------------------------------------------------------------------------
__global__ __launch_bounds__(256, 4) void out_mfma(
    const unsigned short* __restrict__ Hd, const unsigned short* __restrict__ Wot,
    const float* __restrict__ bias, float* __restrict__ Out)
{
    const int t = threadIdx.x;
    const int w = t >> 6, lane = t & 63;
    const int quad = lane >> 4, l15 = lane & 15;
    const int m0 = blockIdx.x * 128, n0 = blockIdx.y * 64;
    const int bb = m0 >> 11, s0 = m0 & (S_ - 1);

    const f32x4 zero = {0.f, 0.f, 0.f, 0.f};
    f32x4 acc[2][4];
    #pragma unroll
    for (int i = 0; i < 2; ++i)
        #pragma unroll
        for (int j = 0; j < 4; ++j) acc[i][j] = zero;

    #pragma unroll 2
    for (int kb0 = 0; kb0 < H_; kb0 += 64) {
        const int hk = kb0 >> 6;
        const size_t hdbase = ((size_t)bb * NH_ + hk) * S_;
        #pragma unroll
        for (int ks = 0; ks < 2; ++ks) {
            const int dc = ks * 32 + quad * 8;
            bf16x8 af[2], bfr[4];
            #pragma unroll
            for (int i = 0; i < 2; ++i) {
                const int s = s0 + w * 32 + i * 16 + l15;
                af[i] = *(const bf16x8*)(Hd + (hdbase + s) * D_ + dc);
            }
            #pragma unroll
            for (int j = 0; j < 4; ++j)
                bfr[j] = *(const bf16x8*)(Wot + (size_t)(n0 + j * 16 + l15) * H_ + kb0 + dc);
            #pragma unroll
            for (int i = 0; i < 2; ++i)
                #pragma unroll
                for (int j = 0; j < 4; ++j)
                    acc[i][j] = MFMA16(af[i], bfr[j], acc[i][j]);
        }
    }
    #pragma unroll
    for (int i = 0; i < 2; ++i)
        #pragma unroll
        for (int r = 0; r < 4; ++r) {
            const int m = m0 + w * 32 + i * 16 + quad * 4 + r;
            #pragma unroll
            for (int j = 0; j < 4; ++j) {
                const int n = n0 + j * 16 + l15;
                Out[(size_t)m * H_ + n] = acc[i][j][r] + bias[n];
            }
        }
}

// ---------------------------------------------------------------------------
__global__ void fill_kernel(float* __restrict__ out, float val, int n) {
    const int i = blockIdx.x * 256 + threadIdx.x;
    if (i < n) out[i] = val;
}

// ---------------------------------------------------------------------------
extern "C" void kernel_launch(void* const* d_in, const int* in_sizes, int n_in,
                              void* d_out, int out_size, void* d_ws, size_t ws_size,
                              hipStream_t stream) {
    const float* q   = (const float*)d_in[0];
    const float* k   = (const float*)d_in[1];
    const float* v   = (const float*)d_in[2];
    const float* k_b = (const float*)d_in[3];
    const int*   msk = (const int*)d_in[4];
    const float* Wq  = (const float*)d_in[5];
    const float* bq  = (const float*)d_in[6];
    const float* Wk  = (const float*)d_in[7];
    const float* bk  = (const float*)d_in[8];
    const float* Wv  = (const float*)d_in[9];
    const float* bv  = (const float*)d_in[10];
    const float* Wkb = (const float*)d_in[11];
    const float* bkb = (const float*)d_in[12];
    const float* Wo  = (const float*)d_in[13];
    const float* bo  = (const float*)d_in[14];
    float* out = (float*)d_out;

    const size_t PER  = (size_t)B_ * NH_ * S_ * D_;
    const size_t NEED = 3 * PER * sizeof(unsigned short);   // 24 MiB (proven)
    if (ws_size < NEED) {   // tripwire (dead path)
        fill_kernel<<<(out_size + 255) / 256, 256, 0, stream>>>(
            out, (float)((ws_size >> 20) + 2), out_size);
        return;
    }
    unsigned short* wsh = (unsigned short*)d_ws;
    unsigned short* Qf  = wsh;              // Q head-major; becomes Hd after attn
    unsigned short* Kf  = wsh + PER;        // K' head-major; Wo_t scratch after attn
    unsigned short* Vf  = wsh + 2 * PER;    // V transposed [b,h,d,s]

    // d_out doubles as scratch for the 4 projection weights (2 MiB of 16.8 MiB)
    unsigned short* Wt = (unsigned short*)d_out;

    dim3 gw(8, 8, 4);
    prep_w<<<gw, 256, 0, stream>>>(Wq, Wk, Wkb, Wv, Wt);

    dim3 gp((B_ * S_) / 128, H_ / 64, 3);   // 64 x 8 x 3  (x = m: XCD-local A reuse)
    proj_all<<<gp, 256, 0, stream>>>(q, k, v, k_b, Wt, bq, bk, bkb, bv, Qf, Kf, Vf);

    dim3 ga(S_ / 128, NH_, B_);             // 16 x 8 x 4
    attn_mfma<<<ga, 256, 0, stream>>>(Qf, Kf, Vf, msk);

    // Kf is dead after attn: reuse it for transposed Wo.
    dim3 gw1(8, 8, 1);
    prep_w<<<gw1, 256, 0, stream>>>(Wo, Wo, Wo, Wo, Kf);

    dim3 go((B_ * S_) / 128, H_ / 64, 1);   // 64 x 8  (x = m)
    out_mfma<<<go, 256, 0, stream>>>(Qf, Kf, bo, out);
}